// Round 2
// baseline (1775.642 us; speedup 1.0000x reference)
//
#include <hip/hip_runtime.h>
#include <hip/hip_bf16.h>
#include <math.h>

#define N_FEAT 32
#define N_HID  64   // 2*N_FEAT
#define N_LAT  64
#define R_HID  128  // 2*N_LAT
#define TPT    8    // tracks per thread (contiguous -> exploits sorted ids)

// ---------------------------------------------------------------------------
// Kernel 1: fused phi MLP + segment-sum pooling.
// Each thread processes TPT contiguous tracks, accumulating the phi output in
// registers while the event id is unchanged; flushes via atomicAdd on change.
// Weights are read with wave-uniform indices -> scalar loads (SGPR operand to
// v_fma), so there is zero LDS pressure.
//
// __launch_bounds__(256, 2): live set is h1[64]+acc[64]+h2[16]+misc ~ 165
// VGPRs. The default heuristic capped at 80 VGPRs and spilled ~650 MB of
// scratch traffic per launch (round-1 rocprof: WRITE_SIZE 675 MB, VALUBusy
// 20%). Allowing up to 256 VGPRs (2 waves/EU) keeps everything in registers.
// ---------------------------------------------------------------------------
__global__ __launch_bounds__(256, 2) void phi_pool_kernel(
    const float* __restrict__ x,
    const int*   __restrict__ eids,
    const float* __restrict__ w1, const float* __restrict__ b1,
    const float* __restrict__ w2, const float* __restrict__ b2,
    float* __restrict__ pooled, int n_tracks)
{
    long long start = (long long)(blockIdx.x * blockDim.x + threadIdx.x) * TPT;
    if (start >= n_tracks) return;

    float acc[N_LAT];
    int cur = -1;

    #pragma unroll 1
    for (int t = 0; t < TPT; ++t) {
        long long tr = start + t;
        if (tr >= n_tracks) break;
        int e = eids[tr];
        if (e != cur) {
            if (cur >= 0) {
                float* dst = pooled + (size_t)cur * N_LAT;
                #pragma unroll
                for (int m = 0; m < N_LAT; ++m) atomicAdd(dst + m, acc[m]);
            }
            cur = e;
            #pragma unroll
            for (int m = 0; m < N_LAT; ++m) acc[m] = 0.f;
        }

        // ---- layer 1: h1 = relu(x @ W1 + b1), x row is 32 floats ----
        float h1[N_HID];
        #pragma unroll
        for (int j = 0; j < N_HID; ++j) h1[j] = b1[j];

        const float4* xp = reinterpret_cast<const float4*>(x + (size_t)tr * N_FEAT);
        #pragma unroll 1
        for (int k4 = 0; k4 < N_FEAT / 4; ++k4) {
            float4 v = xp[k4];
            float xs[4] = {v.x, v.y, v.z, v.w};
            #pragma unroll
            for (int kk = 0; kk < 4; ++kk) {
                float xv = xs[kk];
                const float* wrow = w1 + (size_t)(k4 * 4 + kk) * N_HID;
                #pragma unroll
                for (int j = 0; j < N_HID; ++j) h1[j] += xv * wrow[j];
            }
        }
        #pragma unroll
        for (int j = 0; j < N_HID; ++j) h1[j] = fmaxf(h1[j], 0.f);

        // ---- layer 2: acc += relu(h1 @ W2 + b2), grouped by 16 outputs ----
        #pragma unroll
        for (int mg = 0; mg < N_LAT; mg += 16) {
            float h2[16];
            #pragma unroll
            for (int mm = 0; mm < 16; ++mm) h2[mm] = b2[mg + mm];
            #pragma unroll
            for (int j = 0; j < N_HID; ++j) {
                float hj = h1[j];
                const float* wrow = w2 + (size_t)j * N_LAT + mg;
                #pragma unroll
                for (int mm = 0; mm < 16; ++mm) h2[mm] += hj * wrow[mm];
            }
            #pragma unroll
            for (int mm = 0; mm < 16; ++mm) acc[mg + mm] += fmaxf(h2[mm], 0.f);
        }
    }

    if (cur >= 0) {
        float* dst = pooled + (size_t)cur * N_LAT;
        #pragma unroll
        for (int m = 0; m < N_LAT; ++m) atomicAdd(dst + m, acc[m]);
    }
}

// ---------------------------------------------------------------------------
// Kernel 2: rho MLP per event + sigmoid. One thread per event.
// r1[128] + r2[16] ~ 150 VGPRs live -> same launch-bounds treatment.
// ---------------------------------------------------------------------------
__global__ __launch_bounds__(256, 2) void rho_kernel(
    const float* __restrict__ pooled,
    const float* __restrict__ w1, const float* __restrict__ b1,
    const float* __restrict__ w2, const float* __restrict__ b2,
    const float* __restrict__ w3, const float* __restrict__ b3,
    float* __restrict__ out, int n_events)
{
    int e = blockIdx.x * blockDim.x + threadIdx.x;
    if (e >= n_events) return;

    // ---- layer 1: r1 = relu(pooled @ W1 + b1)  [64 -> 128] ----
    float r1[R_HID];
    #pragma unroll
    for (int j = 0; j < R_HID; ++j) r1[j] = b1[j];

    const float4* pp = reinterpret_cast<const float4*>(pooled + (size_t)e * N_LAT);
    #pragma unroll 1
    for (int k4 = 0; k4 < N_LAT / 4; ++k4) {
        float4 v = pp[k4];
        float xs[4] = {v.x, v.y, v.z, v.w};
        #pragma unroll
        for (int kk = 0; kk < 4; ++kk) {
            float xv = xs[kk];
            const float* wrow = w1 + (size_t)(k4 * 4 + kk) * R_HID;
            #pragma unroll
            for (int j = 0; j < R_HID; ++j) r1[j] += xv * wrow[j];
        }
    }
    #pragma unroll
    for (int j = 0; j < R_HID; ++j) r1[j] = fmaxf(r1[j], 0.f);

    // ---- layer 2+3 fused: z = b3 + sum_m relu(r1 @ W2 + b2)[m] * w3[m] ----
    float z = b3[0];
    #pragma unroll
    for (int mg = 0; mg < N_LAT; mg += 16) {
        float r2[16];
        #pragma unroll
        for (int mm = 0; mm < 16; ++mm) r2[mm] = b2[mg + mm];
        #pragma unroll
        for (int j = 0; j < R_HID; ++j) {
            float rj = r1[j];
            const float* wrow = w2 + (size_t)j * N_LAT + mg;
            #pragma unroll
            for (int mm = 0; mm < 16; ++mm) r2[mm] += rj * wrow[mm];
        }
        #pragma unroll
        for (int mm = 0; mm < 16; ++mm) z += fmaxf(r2[mm], 0.f) * w3[mg + mm];
    }

    out[e] = 1.f / (1.f + expf(-z));
}

extern "C" void kernel_launch(void* const* d_in, const int* in_sizes, int n_in,
                              void* d_out, int out_size, void* d_ws, size_t ws_size,
                              hipStream_t stream) {
    const float* x      = (const float*)d_in[0];
    const int*   eids   = (const int*)  d_in[1];
    const float* phi_w1 = (const float*)d_in[2];
    const float* phi_b1 = (const float*)d_in[3];
    const float* phi_w2 = (const float*)d_in[4];
    const float* phi_b2 = (const float*)d_in[5];
    const float* rho_w1 = (const float*)d_in[6];
    const float* rho_b1 = (const float*)d_in[7];
    const float* rho_w2 = (const float*)d_in[8];
    const float* rho_b2 = (const float*)d_in[9];
    const float* rho_w3 = (const float*)d_in[10];
    const float* rho_b3 = (const float*)d_in[11];
    float* out = (float*)d_out;

    int n_tracks = in_sizes[1];
    int n_events = out_size;

    float* pooled = (float*)d_ws;  // [n_events, 64] accumulator
    hipMemsetAsync(pooled, 0, (size_t)n_events * N_LAT * sizeof(float), stream);

    int n_threads = (n_tracks + TPT - 1) / TPT;
    int n_blocks  = (n_threads + 255) / 256;
    phi_pool_kernel<<<n_blocks, 256, 0, stream>>>(
        x, eids, phi_w1, phi_b1, phi_w2, phi_b2, pooled, n_tracks);

    int r_blocks = (n_events + 255) / 256;
    rho_kernel<<<r_blocks, 256, 0, stream>>>(
        pooled, rho_w1, rho_b1, rho_w2, rho_b2, rho_w3, rho_b3, out, n_events);
}

// Round 3
// 1587.095 us; speedup vs baseline: 1.1188x; 1.1188x over previous
//
#include <hip/hip_runtime.h>
#include <hip/hip_bf16.h>
#include <math.h>

#define N_FEAT 32
#define N_HID  64   // 2*N_FEAT
#define N_LAT  64
#define R_HID  128  // 2*N_LAT
#define TPT    8    // tracks per thread (contiguous -> exploits sorted ids)

// ext_vector values are SSA (never demoted to scratch with constant indices).
typedef float f32x16 __attribute__((ext_vector_type(16)));
typedef float f32x4  __attribute__((ext_vector_type(4)));

// ---------------------------------------------------------------------------
// Kernel 1: fused phi MLP + segment-sum pooling.
// All per-thread state lives in named ext-vectors -> no allocas -> no scratch
// (round-2 rocprof: float arrays were demoted to local memory, VGPR=80,
// VALUBusy 20%, latency-bound on cached scratch).
// Layer 2 is folded into layer 1 group completion so h1 is only ever 16 wide.
// Weights are wave-uniform -> s_load (SGPR operand to v_fma), no LDS.
// ---------------------------------------------------------------------------
__global__ __launch_bounds__(256, 2) void phi_pool_kernel(
    const float* __restrict__ x,
    const int*   __restrict__ eids,
    const float* __restrict__ w1, const float* __restrict__ b1,
    const float* __restrict__ w2, const float* __restrict__ b2,
    float* __restrict__ pooled, int n_tracks)
{
    long long start = (long long)(blockIdx.x * blockDim.x + threadIdx.x) * TPT;
    if (start >= n_tracks) return;

    f32x16 acc0, acc1, acc2, acc3;   // per-event pooled accumulator (64)
    #pragma unroll
    for (int i = 0; i < 16; ++i) { acc0[i] = 0.f; acc1[i] = 0.f; acc2[i] = 0.f; acc3[i] = 0.f; }
    int cur = -1;

    #pragma unroll 1
    for (int t = 0; t < TPT; ++t) {
        long long tr = start + t;
        if (tr >= n_tracks) break;
        int e = eids[tr];
        if (e != cur) {
            if (cur >= 0) {
                float* dst = pooled + (size_t)cur * N_LAT;
                #pragma unroll
                for (int mm = 0; mm < 16; ++mm) {
                    atomicAdd(dst + mm,      acc0[mm]);
                    atomicAdd(dst + 16 + mm, acc1[mm]);
                    atomicAdd(dst + 32 + mm, acc2[mm]);
                    atomicAdd(dst + 48 + mm, acc3[mm]);
                }
            }
            cur = e;
            #pragma unroll
            for (int i = 0; i < 16; ++i) { acc0[i] = 0.f; acc1[i] = 0.f; acc2[i] = 0.f; acc3[i] = 0.f; }
        }

        // x row (32 floats) hoisted into 8 named f32x4 -> 32 VGPRs, loaded once
        const f32x4* xp = reinterpret_cast<const f32x4*>(x + (size_t)tr * N_FEAT);
        f32x4 xv0 = xp[0], xv1 = xp[1], xv2 = xp[2], xv3 = xp[3],
              xv4 = xp[4], xv5 = xp[5], xv6 = xp[6], xv7 = xp[7];

        f32x16 h2_0, h2_1, h2_2, h2_3;   // pre-bias layer-2 accumulator (64)
        #pragma unroll
        for (int i = 0; i < 16; ++i) { h2_0[i] = 0.f; h2_1[i] = 0.f; h2_2[i] = 0.f; h2_3[i] = 0.f; }

        // rolled over 4 groups of 16 h1 outputs: body ~1.6k instrs, I-cache-safe
        #pragma unroll 1
        for (int g = 0; g < 4; ++g) {
            const int jbase = g * 16;
            f32x16 h1g;
            #pragma unroll
            for (int jj = 0; jj < 16; ++jj) h1g[jj] = b1[jbase + jj];

            // layer 1, group g: h1g[jj] += sum_k x[k] * W1[k][jbase+jj]
            #define L1K(XV, KBASE)                                                  \
                _Pragma("unroll")                                                   \
                for (int kk = 0; kk < 4; ++kk) {                                    \
                    float xk = (XV)[kk];                                            \
                    const float* wr = w1 + (size_t)((KBASE) + kk) * N_HID + jbase;  \
                    _Pragma("unroll")                                               \
                    for (int jj = 0; jj < 16; ++jj)                                 \
                        h1g[jj] = fmaf(xk, wr[jj], h1g[jj]);                        \
                }
            L1K(xv0, 0)  L1K(xv1, 4)  L1K(xv2, 8)  L1K(xv3, 12)
            L1K(xv4, 16) L1K(xv5, 20) L1K(xv6, 24) L1K(xv7, 28)
            #undef L1K

            #pragma unroll
            for (int jj = 0; jj < 16; ++jj) h1g[jj] = fmaxf(h1g[jj], 0.f);

            // layer 2 partial: h2 += h1g . W2[jbase..jbase+15][:]
            #pragma unroll
            for (int jj = 0; jj < 16; ++jj) {
                float hj = h1g[jj];
                const float* wr = w2 + (size_t)(jbase + jj) * N_LAT;
                #pragma unroll
                for (int mm = 0; mm < 16; ++mm) {
                    h2_0[mm] = fmaf(hj, wr[mm],      h2_0[mm]);
                    h2_1[mm] = fmaf(hj, wr[16 + mm], h2_1[mm]);
                    h2_2[mm] = fmaf(hj, wr[32 + mm], h2_2[mm]);
                    h2_3[mm] = fmaf(hj, wr[48 + mm], h2_3[mm]);
                }
            }
        }

        // bias + relu + pool into the running event accumulator
        #pragma unroll
        for (int mm = 0; mm < 16; ++mm) {
            acc0[mm] += fmaxf(h2_0[mm] + b2[mm],      0.f);
            acc1[mm] += fmaxf(h2_1[mm] + b2[16 + mm], 0.f);
            acc2[mm] += fmaxf(h2_2[mm] + b2[32 + mm], 0.f);
            acc3[mm] += fmaxf(h2_3[mm] + b2[48 + mm], 0.f);
        }
    }

    if (cur >= 0) {
        float* dst = pooled + (size_t)cur * N_LAT;
        #pragma unroll
        for (int mm = 0; mm < 16; ++mm) {
            atomicAdd(dst + mm,      acc0[mm]);
            atomicAdd(dst + 16 + mm, acc1[mm]);
            atomicAdd(dst + 32 + mm, acc2[mm]);
            atomicAdd(dst + 48 + mm, acc3[mm]);
        }
    }
}

// ---------------------------------------------------------------------------
// Kernel 2: rho MLP per event + sigmoid. One thread per event.
// Same vector-SSA structure: r1 computed in 16-wide groups, layer-2/3 folded.
// ---------------------------------------------------------------------------
__global__ __launch_bounds__(256, 2) void rho_kernel(
    const float* __restrict__ pooled,
    const float* __restrict__ w1, const float* __restrict__ b1,
    const float* __restrict__ w2, const float* __restrict__ b2,
    const float* __restrict__ w3, const float* __restrict__ b3,
    float* __restrict__ out, int n_events)
{
    int e = blockIdx.x * blockDim.x + threadIdx.x;
    if (e >= n_events) return;

    const f32x16* pp = reinterpret_cast<const f32x16*>(pooled + (size_t)e * N_LAT);
    f32x16 pv0 = pp[0], pv1 = pp[1], pv2 = pp[2], pv3 = pp[3];

    f32x16 r2_0, r2_1, r2_2, r2_3;   // pre-bias layer-2 accumulator (64)
    #pragma unroll
    for (int i = 0; i < 16; ++i) { r2_0[i] = 0.f; r2_1[i] = 0.f; r2_2[i] = 0.f; r2_3[i] = 0.f; }

    #pragma unroll 1
    for (int g = 0; g < 8; ++g) {
        const int jbase = g * 16;
        f32x16 r1g;
        #pragma unroll
        for (int jj = 0; jj < 16; ++jj) r1g[jj] = b1[jbase + jj];

        // layer 1, group g: r1g[jj] += sum_k pooled[k] * W1[k][jbase+jj]
        #define RL1(PV, KBASE)                                                      \
            _Pragma("unroll")                                                       \
            for (int kk = 0; kk < 16; ++kk) {                                       \
                float xk = (PV)[kk];                                                \
                const float* wr = w1 + (size_t)((KBASE) + kk) * R_HID + jbase;      \
                _Pragma("unroll")                                                   \
                for (int jj = 0; jj < 16; ++jj)                                     \
                    r1g[jj] = fmaf(xk, wr[jj], r1g[jj]);                            \
            }
        RL1(pv0, 0) RL1(pv1, 16) RL1(pv2, 32) RL1(pv3, 48)
        #undef RL1

        #pragma unroll
        for (int jj = 0; jj < 16; ++jj) r1g[jj] = fmaxf(r1g[jj], 0.f);

        // layer 2 partial
        #pragma unroll
        for (int jj = 0; jj < 16; ++jj) {
            float rj = r1g[jj];
            const float* wr = w2 + (size_t)(jbase + jj) * N_LAT;
            #pragma unroll
            for (int mm = 0; mm < 16; ++mm) {
                r2_0[mm] = fmaf(rj, wr[mm],      r2_0[mm]);
                r2_1[mm] = fmaf(rj, wr[16 + mm], r2_1[mm]);
                r2_2[mm] = fmaf(rj, wr[32 + mm], r2_2[mm]);
                r2_3[mm] = fmaf(rj, wr[48 + mm], r2_3[mm]);
            }
        }
    }

    // bias + relu + dot with w3 + sigmoid
    float z = b3[0];
    #pragma unroll
    for (int mm = 0; mm < 16; ++mm) {
        z += fmaxf(r2_0[mm] + b2[mm],      0.f) * w3[mm];
        z += fmaxf(r2_1[mm] + b2[16 + mm], 0.f) * w3[16 + mm];
        z += fmaxf(r2_2[mm] + b2[32 + mm], 0.f) * w3[32 + mm];
        z += fmaxf(r2_3[mm] + b2[48 + mm], 0.f) * w3[48 + mm];
    }
    out[e] = 1.f / (1.f + expf(-z));
}

extern "C" void kernel_launch(void* const* d_in, const int* in_sizes, int n_in,
                              void* d_out, int out_size, void* d_ws, size_t ws_size,
                              hipStream_t stream) {
    const float* x      = (const float*)d_in[0];
    const int*   eids   = (const int*)  d_in[1];
    const float* phi_w1 = (const float*)d_in[2];
    const float* phi_b1 = (const float*)d_in[3];
    const float* phi_w2 = (const float*)d_in[4];
    const float* phi_b2 = (const float*)d_in[5];
    const float* rho_w1 = (const float*)d_in[6];
    const float* rho_b1 = (const float*)d_in[7];
    const float* rho_w2 = (const float*)d_in[8];
    const float* rho_b2 = (const float*)d_in[9];
    const float* rho_w3 = (const float*)d_in[10];
    const float* rho_b3 = (const float*)d_in[11];
    float* out = (float*)d_out;

    int n_tracks = in_sizes[1];
    int n_events = out_size;

    float* pooled = (float*)d_ws;  // [n_events, 64] accumulator
    hipMemsetAsync(pooled, 0, (size_t)n_events * N_LAT * sizeof(float), stream);

    int n_threads = (n_tracks + TPT - 1) / TPT;
    int n_blocks  = (n_threads + 255) / 256;
    phi_pool_kernel<<<n_blocks, 256, 0, stream>>>(
        x, eids, phi_w1, phi_b1, phi_w2, phi_b2, pooled, n_tracks);

    int r_blocks = (n_events + 255) / 256;
    rho_kernel<<<r_blocks, 256, 0, stream>>>(
        pooled, rho_w1, rho_b1, rho_w2, rho_b2, rho_w3, rho_b3, out, n_events);
}